// Round 6
// baseline (258.152 us; speedup 1.0000x reference)
//
#include <hip/hip_runtime.h>

// ---------------------------------------------------------------------------
// GroupAgent fused pipeline v6, MI355X (gfx950), fp16 MFMA + f32 accumulate.
// Key change vs v5: all heavy kernels use 128 rows/WAVE (8 row-tiles) to halve
// per-CU LDS B-tile re-reads (LDS-BW was the wall: 8 waves x 16KB re-read).
// final: 1 block/CU, 1 wave/SIMD, 512-VGPR budget (waves_per_eu(1,1)),
// ga[8][8] resident, ring-3 LDS + counted vmcnt, b_dyn K-sliced across by.
// ---------------------------------------------------------------------------

typedef _Float16 half8 __attribute__((ext_vector_type(8)));
typedef _Float16 half4 __attribute__((ext_vector_type(4)));
typedef float f32x4 __attribute__((ext_vector_type(4)));

#define MFMA16(a, b, c) __builtin_amdgcn_mfma_f32_16x16x32_f16((a), (b), (c), 0, 0, 0)

constexpr int NROWS = 16384;

__device__ __forceinline__ float sigmoidf_(float x) { return 1.0f / (1.0f + __expf(-x)); }

__device__ __forceinline__ void glds16(const void* g, void* l) {
    __builtin_amdgcn_global_load_lds((const __attribute__((address_space(1))) void*)g,
                                     (__attribute__((address_space(3))) void*)l, 16, 0, 0);
}

// ---------------- prep: x -> x16, h -> xh[:,256:512] ----------------
__global__ void cvt_kernel(const float* __restrict__ x, const float* __restrict__ h,
                           _Float16* __restrict__ x16, _Float16* __restrict__ xh) {
    int b = blockIdx.x;
    if (b < 4096) {
        int i = (b * 256 + threadIdx.x) * 4;
        float4 v = *reinterpret_cast<const float4*>(x + i);
        x16[i + 0] = (_Float16)v.x; x16[i + 1] = (_Float16)v.y;
        x16[i + 2] = (_Float16)v.z; x16[i + 3] = (_Float16)v.w;
    } else {
        int i = ((b - 4096) * 256 + threadIdx.x) * 4;
        float4 v = *reinterpret_cast<const float4*>(h + i);
        int n = i >> 8, j = i & 255;
        _Float16* o = xh + n * 512 + 256 + j;
        o[0] = (_Float16)v.x; o[1] = (_Float16)v.y;
        o[2] = (_Float16)v.z; o[3] = (_Float16)v.w;
    }
}

// ---------------- prep: unified weight transpose+swizzle (K=256 segs) ----------------
__global__ void wtrans_kernel(const float* __restrict__ s0, const float* __restrict__ s1,
                              const float* __restrict__ s2, const float* __restrict__ s3,
                              const float* __restrict__ s4, _Float16* __restrict__ d0,
                              _Float16* __restrict__ d1, _Float16* __restrict__ d2,
                              _Float16* __restrict__ d3, _Float16* __restrict__ d4) {
    __shared__ float tile[32][33];
    int b = blockIdx.x;
    const float* src; _Float16* dst; int C, idx;
    if (b < 64)       { src = s0; dst = d0; C = 256;  idx = b; }
    else if (b < 128) { src = s1; dst = d1; C = 256;  idx = b - 64; }
    else if (b < 192) { src = s2; dst = d2; C = 256;  idx = b - 128; }
    else if (b < 200) { src = s3; dst = d3; C = 32;   idx = b - 192; }
    else              { src = s4; dst = d4; C = 8192; idx = b - 200; }
    int kb = (idx & 7) * 32, cb = (idx >> 3) * 32;
    int tx = threadIdx.x, ty = threadIdx.y;  // 32 x 8
#pragma unroll
    for (int i = ty; i < 32; i += 8) tile[i][tx] = src[(kb + i) * C + cb + tx];
    __syncthreads();
#pragma unroll
    for (int i = ty; i < 32; i += 8) {
        int c = cb + i, k = kb + tx;
        dst[c * 256 + (k ^ ((c & 7) << 3))] = (_Float16)tile[tx][i];
    }
}

// ---------------- prep: GRU weight pack, coalesced tile transpose ----------------
__global__ void wgru_prep_kernel(const float* __restrict__ gwih, const float* __restrict__ gwhh,
                                 _Float16* __restrict__ wgru) {
    __shared__ float tile[32][33];
    int b = blockIdx.x, job = b >> 6, idx = b & 63;
    int kb = (idx & 7) * 32, cb = (idx >> 3) * 32;
    const float* src = (job & 1) ? gwhh : gwih;
    int coff = (job >> 1) * 256;
    int gate = (job < 4) ? (job >> 1) : (2 + (job & 1));
    int koff = (job & 1) * 256;
    int tx = threadIdx.x, ty = threadIdx.y;  // 32 x 8
#pragma unroll
    for (int i = ty; i < 32; i += 8) tile[i][tx] = src[(kb + i) * 768 + coff + cb + tx];
    __syncthreads();
#pragma unroll
    for (int i = ty; i < 32; i += 8) {
        int c = cb + i;
        int row = (c >> 4) * 64 + gate * 16 + (c & 15);
        int kk = kb + tx + koff;
        wgru[row * 512 + (kk ^ ((row & 7) << 3))] = (_Float16)tile[tx][i];
    }
}

// ---------------- GEMM + bias + activation, LDS-staged B, 8 row-tiles/wave ----------------
// out[M][ONC] = act(A[M][256] @ W + bias); Wt swizzled [C][256].
// grid (32, C/64), block 256 = 4 waves x 128 rows = 512 rows.
template <int ACT>  // 1 relu, 2 tanh
__global__ __launch_bounds__(256, 2) void gemm_lds_kernel(
    const _Float16* __restrict__ Am, const _Float16* __restrict__ Wt,
    const float* __restrict__ bias, _Float16* __restrict__ out16, int ONC) {
    __shared__ _Float16 Bs[64 * 256];  // 32 KB
    const int tid = threadIdx.x, wave = tid >> 6, lane = tid & 63;
    const int r = lane & 15, kg = lane >> 4;
    const int row0 = blockIdx.x * 512 + wave * 128;
    const int col0 = blockIdx.y * 64;
    const _Float16* src = Wt + col0 * 256;
#pragma unroll
    for (int it = 0; it < 8; ++it)
        glds16(src + it * 2048 + tid * 8, Bs + it * 2048 + tid * 8);
    asm volatile("s_waitcnt vmcnt(0)" ::: "memory");
    __syncthreads();

    f32x4 z = {0.f, 0.f, 0.f, 0.f};
    f32x4 acc[8][4];
#pragma unroll
    for (int t = 0; t < 8; t++)
#pragma unroll
        for (int j = 0; j < 4; j++) acc[t][j] = z;
    const int swz = (r & 7) << 4;
#pragma unroll
    for (int kb = 0; kb < 8; kb++) {
        half8 a[8], bm[4];
#pragma unroll
        for (int t = 0; t < 8; t++)
            a[t] = *reinterpret_cast<const half8*>(Am + (row0 + t * 16 + r) * 256 + kb * 32 + kg * 8);
#pragma unroll
        for (int j = 0; j < 4; j++)
            bm[j] = *reinterpret_cast<const half8*>(
                (const char*)Bs + (j * 16 + r) * 512 + ((kb * 64 + kg * 16) ^ swz));
#pragma unroll
        for (int t = 0; t < 8; t++)
#pragma unroll
            for (int j = 0; j < 4; j++) acc[t][j] = MFMA16(a[t], bm[j], acc[t][j]);
    }
#pragma unroll
    for (int j = 0; j < 4; j++) {
        int cc = col0 + j * 16 + r;
        float bv = bias[cc];
#pragma unroll
        for (int t = 0; t < 8; t++)
#pragma unroll
            for (int i = 0; i < 4; i++) {
                int rr = row0 + t * 16 + kg * 4 + i;
                float v = acc[t][j][i] + bv;
                if (ACT == 1) v = fmaxf(v, 0.0f);
                if (ACT == 2) v = tanhf(v);
                out16[rr * ONC + cc] = (_Float16)v;
            }
    }
}

// ---------------- fused GRU: one GEMM + gate epilogue, 8 row-tiles/wave ----------------
// grid (32, 16), block 256 = 4 waves x 128 rows.
__global__ __launch_bounds__(256, 2) void gru_kernel(
    const _Float16* __restrict__ xh, const float* __restrict__ hf,
    const _Float16* __restrict__ wgru, const float* __restrict__ bih,
    const float* __restrict__ bhh, _Float16* __restrict__ hn16) {
    __shared__ _Float16 Bs[64 * 512];  // 64 KB
    const int tid = threadIdx.x, wave = tid >> 6, lane = tid & 63;
    const int r = lane & 15, kg = lane >> 4;
    const int row0 = blockIdx.x * 512 + wave * 128;
    const int c0 = blockIdx.y * 16;
    const _Float16* src = wgru + (size_t)blockIdx.y * 64 * 512;
#pragma unroll
    for (int it = 0; it < 16; ++it)
        glds16(src + it * 2048 + tid * 8, Bs + it * 2048 + tid * 8);
    asm volatile("s_waitcnt vmcnt(0)" ::: "memory");
    __syncthreads();

    f32x4 z = {0.f, 0.f, 0.f, 0.f};
    f32x4 acc[8][4];  // [row-tile][gate]
#pragma unroll
    for (int t = 0; t < 8; t++)
#pragma unroll
        for (int j = 0; j < 4; j++) acc[t][j] = z;
    const int swz = (r & 7) << 4;
#pragma unroll
    for (int kb = 0; kb < 16; kb++) {
        half8 a[8], bm[4];
#pragma unroll
        for (int t = 0; t < 8; t++)
            a[t] = *reinterpret_cast<const half8*>(xh + (row0 + t * 16 + r) * 512 + kb * 32 + kg * 8);
#pragma unroll
        for (int j = 0; j < 4; j++)
            bm[j] = *reinterpret_cast<const half8*>(
                (const char*)Bs + (j * 16 + r) * 1024 + ((kb * 64 + kg * 16) ^ swz));
#pragma unroll
        for (int t = 0; t < 8; t++)
#pragma unroll
            for (int j = 0; j < 4; j++) acc[t][j] = MFMA16(a[t], bm[j], acc[t][j]);
    }
    const int cc = c0 + r;
    float brz = bih[cc] + bhh[cc];
    float bzz = bih[256 + cc] + bhh[256 + cc];
    float bin = bih[512 + cc], bhn = bhh[512 + cc];
#pragma unroll
    for (int t = 0; t < 8; t++)
#pragma unroll
        for (int i = 0; i < 4; i++) {
            int rr = row0 + t * 16 + kg * 4 + i;
            float rg = sigmoidf_(acc[t][0][i] + brz);
            float zg = sigmoidf_(acc[t][1][i] + bzz);
            float nn = tanhf(acc[t][2][i] + bin + rg * (acc[t][3][i] + bhn));
            float v = (1.0f - zg) * nn + zg * hf[rr * 256 + cc];
            hn16[rr * 256 + cc] = (_Float16)v;
        }
}

// ---------------- hn16 [N][256] -> hnT16 [256][N] f16, coalesced ----------------
__global__ void hnt_kernel(const _Float16* __restrict__ hn16, _Float16* __restrict__ hnT16) {
    __shared__ float tile[32][33];
    int r0 = blockIdx.x * 32, c0 = blockIdx.y * 32;
    int tx = threadIdx.x, ty = threadIdx.y;  // 32 x 8
#pragma unroll
    for (int i = ty; i < 32; i += 8) tile[i][tx] = (float)hn16[(r0 + i) * 256 + c0 + tx];
    __syncthreads();
#pragma unroll
    for (int i = ty; i < 32; i += 8)
        hnT16[(size_t)(c0 + i) * NROWS + r0 + tx] = (_Float16)tile[tx][i];
}

// ---------------- fused final stage: 8 row-tiles/wave, ring-3, counted vmcnt ----------------
// grid 256 = 32 bx x 8 by (by = bid&7, XCD-pinned h-slice). 1 block/CU.
// Wave = 128 rows x 32 actions; block = 512 rows. ga[8][8] resident under
// the 512-VGPR unified budget (waves_per_eu(1,1), 1 wave/SIMD).
__global__ __launch_bounds__(256)
__attribute__((amdgpu_waves_per_eu(1, 1))) void final_kernel(
    const _Float16* __restrict__ g16, const _Float16* __restrict__ hwt,
    const float* __restrict__ hwb, const _Float16* __restrict__ hbt,
    const float* __restrict__ hbb, const _Float16* __restrict__ hnT16,
    float* __restrict__ q) {
    __shared__ _Float16 Bs[3][8192];   // 48 KB ring, 1 h per chunk
    __shared__ _Float16 hvs[16384];    // 32 KB: hn slice as [h 32][row 512]
    __shared__ float hwbs[1024];       // 4 KB
    const int bid = blockIdx.x;
    const int by = bid & 7, bx = bid >> 3;
    const int tid = threadIdx.x, wave = tid >> 6, lane = tid & 63;
    const int r = lane & 15, kg = lane >> 4;
    const int row0 = bx * 512 + wave * 128;
    const int hbase = by * 32;
    const int swz = (r & 7) << 4;

    // ---- ga loads FIRST (oldest vmem ops -> compiler can wait with counted N) ----
    half8 ga[8][8];
#pragma unroll
    for (int t = 0; t < 8; t++)
#pragma unroll
        for (int kb = 0; kb < 8; kb++)
            ga[t][kb] = *reinterpret_cast<const half8*>(
                g16 + (row0 + t * 16 + r) * 256 + kb * 32 + kg * 8);

    // b_dyn K-slice operands (tiny, issued before the glds batch)
    const int cby = (by * 64 + kg * 16) ^ swz;
    half8 hb0 = *reinterpret_cast<const half8*>((const char*)hbt + r * 512 + cby);
    half8 hb1 = *reinterpret_cast<const half8*>((const char*)hbt + (16 + r) * 512 + cby);

    // ---- prologue staging: hvs(8) + hwbs(1) + chunk0(4) + chunk1(4) = 17 ----
#pragma unroll
    for (int it = 0; it < 8; ++it) {  // hn slice: [32 h][512 rows]
        int e = it * 2048 + tid * 8;
        glds16(hnT16 + (size_t)(hbase + (e >> 9)) * NROWS + bx * 512 + (e & 511), hvs + e);
    }
    glds16(hwb + hbase * 32 + tid * 4, hwbs + tid * 4);
#pragma unroll
    for (int it = 0; it < 4; ++it) {
        int e = it * 2048 + tid * 8;
        glds16(hwt + (size_t)hbase * 8192 + e, &Bs[0][0] + e);
    }
#pragma unroll
    for (int it = 0; it < 4; ++it) {
        int e = it * 2048 + tid * 8;
        glds16(hwt + (size_t)(hbase + 1) * 8192 + e, &Bs[1][0] + e);
    }

    // pin ga resident (non-rematerializable)
#pragma unroll
    for (int t = 0; t < 8; t++)
#pragma unroll
        for (int kb = 0; kb < 8; kb++)
            asm volatile("" : "+v"(ga[t][kb]));

    // ---- qa init (+hbb bias on by==0) and b_dyn K-slice kb==by ----
    f32x4 qa[8][2];
    {
        float b0v = (by == 0) ? hbb[r] : 0.0f;
        float b1v = (by == 0) ? hbb[16 + r] : 0.0f;
#pragma unroll
        for (int t = 0; t < 8; t++) {
            qa[t][0] = {b0v, b0v, b0v, b0v};
            qa[t][1] = {b1v, b1v, b1v, b1v};
        }
#pragma unroll
        for (int t = 0; t < 8; t++) {
            qa[t][0] = MFMA16(ga[t][by], hb0, qa[t][0]);
            qa[t][1] = MFMA16(ga[t][by], hb1, qa[t][1]);
        }
    }

    // ---- main loop: per h one barrier, counted vmcnt (never 0 until tail) ----
    int cur = 0;  // h % 3
    for (int h = 0; h < 32; ++h) {
        if (h < 30)
            asm volatile("s_waitcnt vmcnt(4)" ::: "memory");
        else
            asm volatile("s_waitcnt vmcnt(0)" ::: "memory");
        __builtin_amdgcn_s_barrier();
        if (h < 30) {  // prefetch chunk h+2 into buf (cur+2)%3
            int pre = cur + 2; if (pre >= 3) pre -= 3;
            const _Float16* src = hwt + (size_t)(hbase + h + 2) * 8192;
            _Float16* dst = &Bs[pre][0];
#pragma unroll
            for (int it = 0; it < 4; ++it) {
                int e = it * 2048 + tid * 8;
                glds16(src + e, dst + e);
            }
        }
        const char* bp = (const char*)&Bs[cur][0];
#pragma unroll
        for (int c = 0; c < 2; ++c) {
            float wb = hwbs[(h << 5) + (c << 4) + r];
            f32x4 w[8];
#pragma unroll
            for (int t = 0; t < 8; t++) w[t] = {wb, wb, wb, wb};
#pragma unroll
            for (int kb = 0; kb < 8; kb++) {
                half8 b = *reinterpret_cast<const half8*>(
                    bp + (c * 16 + r) * 512 + ((kb * 64 + kg * 16) ^ swz));
#pragma unroll
                for (int t = 0; t < 8; t++) w[t] = MFMA16(ga[t][kb], b, w[t]);
            }
#pragma unroll
            for (int t = 0; t < 8; t++) {
                half4 hv4 = *reinterpret_cast<const half4*>(
                    hvs + (h << 9) + wave * 128 + t * 16 + kg * 4);
#pragma unroll
                for (int i = 0; i < 4; i++) qa[t][c][i] += (float)hv4[i] * w[t][i];
            }
        }
        cur = cur + 1; if (cur >= 3) cur -= 3;
    }

#pragma unroll
    for (int t = 0; t < 8; t++)
#pragma unroll
        for (int i = 0; i < 4; i++) {
            int rr = row0 + t * 16 + kg * 4 + i;
            atomicAdd(&q[rr * 32 + r], qa[t][0][i]);
            atomicAdd(&q[rr * 32 + 16 + r], qa[t][1][i]);
        }
}

// ---------------------------------------------------------------------------
extern "C" void kernel_launch(void* const* d_in, const int* in_sizes, int n_in,
                              void* d_out, int out_size, void* d_ws, size_t ws_size,
                              hipStream_t stream) {
    const float* x = (const float*)d_in[0];
    const float* h = (const float*)d_in[1];
    const float* fc1_w = (const float*)d_in[2];
    const float* fc1_b = (const float*)d_in[3];
    const float* gwih = (const float*)d_in[4];
    const float* gbih = (const float*)d_in[5];
    const float* gwhh = (const float*)d_in[6];
    const float* gbhh = (const float*)d_in[7];
    const float* hgw1 = (const float*)d_in[8];
    const float* hgb1 = (const float*)d_in[9];
    const float* hgw2 = (const float*)d_in[10];
    const float* hgb2 = (const float*)d_in[11];
    const float* hbw = (const float*)d_in[12];
    const float* hbb = (const float*)d_in[13];
    const float* hww = (const float*)d_in[14];
    const float* hwb = (const float*)d_in[15];
    float* q = (float*)d_out;

    char* p = (char*)d_ws;
    auto alloc = [&](size_t bytes) { char* r = p; p += (bytes + 255) & ~255ULL; return r; };
    _Float16* x16 = (_Float16*)alloc((size_t)NROWS * 256 * 2);
    _Float16* xh = (_Float16*)alloc((size_t)NROWS * 512 * 2);
    _Float16* w1t = (_Float16*)alloc((size_t)256 * 256 * 2);
    _Float16* wgru = (_Float16*)alloc((size_t)1024 * 512 * 2);
    _Float16* hg1t = (_Float16*)alloc((size_t)256 * 256 * 2);
    _Float16* hg2t = (_Float16*)alloc((size_t)256 * 256 * 2);
    _Float16* hbt = (_Float16*)alloc((size_t)32 * 256 * 2);
    _Float16* hwt = (_Float16*)alloc((size_t)8192 * 256 * 2);
    _Float16* hn16 = (_Float16*)alloc((size_t)NROWS * 256 * 2);
    _Float16* hnT16 = (_Float16*)alloc((size_t)256 * NROWS * 2);
    _Float16* t16 = (_Float16*)alloc((size_t)NROWS * 256 * 2);
    _Float16* g16 = (_Float16*)alloc((size_t)NROWS * 256 * 2);

    // ---- prep ----
    cvt_kernel<<<8192, 256, 0, stream>>>(x, h, x16, xh);
    wtrans_kernel<<<2248, dim3(32, 8), 0, stream>>>(fc1_w, hgw1, hgw2, hbw, hww,
                                                    w1t, hg1t, hg2t, hbt, hwt);
    hipMemsetAsync(wgru, 0, (size_t)1024 * 512 * 2, stream);
    wgru_prep_kernel<<<384, dim3(32, 8), 0, stream>>>(gwih, gwhh, wgru);

    hipMemsetAsync(d_out, 0, (size_t)NROWS * 32 * sizeof(float), stream);

    // ---- stage 1: x1 = relu(x @ fc1_w + b) -> xh[:, 0:256] ----
    gemm_lds_kernel<1><<<dim3(32, 4), 256, 0, stream>>>(x16, w1t, fc1_b, xh, 512);

    // ---- stage 2: GRU ----
    gru_kernel<<<dim3(32, 16), 256, 0, stream>>>(xh, h, wgru, gbih, gbhh, hn16);
    hnt_kernel<<<dim3(512, 8), dim3(32, 8), 0, stream>>>(hn16, hnT16);

    // ---- stage 3/4: hypernet latent ----
    gemm_lds_kernel<1><<<dim3(32, 4), 256, 0, stream>>>(hn16, hg1t, hgb1, t16, 256);
    gemm_lds_kernel<2><<<dim3(32, 4), 256, 0, stream>>>(t16, hg2t, hgb2, g16, 256);

    // ---- stage 5: fused b_dyn + w_dyn einsum ----
    final_kernel<<<256, 256, 0, stream>>>(g16, hwt, hwb, hbt, hbb, hnT16, q);
}